// Round 1
// 343.711 us; speedup vs baseline: 1.0190x; 1.0190x over previous
//
#include <hip/hip_runtime.h>
#include <cstdint>
#include <cstddef>

// L1 attention scores on MI355X.
// out[b,s,t,h] = -(1/sqrt(D)) * sum_d |q[b,s,h,d] - k[b,t,h,d]|
// B=2, S=2048, H=8, D=32, fp32.
//
// Round 4 changes (theory: latency-bound at 2 waves/SIMD; occupancy 25%
// because qf[4][8] = 128 VGPRs pushed total into the 129-256 band):
//  - RS 4 -> 2: q fragment file halves to 64 VGPRs; total ~120 VGPRs.
//    __launch_bounds__(256, 4) enforces <=128 VGPR -> 4 waves/SIMD (50%).
//  - TCHUNK 8 -> 16 (each thread computes a 2s x 2t micro-tile per chunk):
//    keeps 256 VALU ops per thread per chunk, halves barrier count to 16.
//    Second t-row read is raddr + 512 f32x4 (rotation swizzle is invariant
//    under row+64, since 64 % 8 == 0) -> same conflict-free pattern.
//  - Grid 2048 -> 4096 blocks (SB=8). LDS 2 x 16 KB; 4 blocks/CU = 128 KB.

#define S_DIM 2048
#define H_DIM 8
#define D_DIM 32
#define RS 2          // s-values per thread (per wave)
#define SB 8          // s-values per block (4 waves * RS)
#define TSPLIT 8      // t-range split across blocks
#define TCHUNK 16     // t-values staged per LDS chunk
#define NTHREADS 256
#define NCH ((S_DIM / TSPLIT) / TCHUNK)   // 16 chunks of 16 t

typedef float f32x4 __attribute__((ext_vector_type(4)));

__global__ __launch_bounds__(NTHREADS, 4) void l1attn_kernel(
    const float* __restrict__ q, const float* __restrict__ k,
    float* __restrict__ out)
{
  // Chunk element (t_sub, h, d): row = 8*t_sub + h (0..127), dv = d>>2,
  // stored at f32x4 index f4 = row*8 + ((dv+row)&7)  (rotation swizzle).
  __shared__ float ldsk[2][TCHUNK * H_DIM * D_DIM];  // 2 x 16 KB

  const int tid  = threadIdx.x;
  const int lane = tid & 63;
  const int wave = tid >> 6;

  const int bid = blockIdx.x;
  const int b   = bid >> 11;         // 2048 blocks per batch element
  const int rem = bid & 2047;
  const int sg  = rem >> 3;          // s-group 0..255
  const int tq  = rem & 7;           // t-eighth 0..7

  const int h      = lane & 7;
  const int t_sub  = lane >> 3;
  const int s_base = sg * SB + wave * RS;
  const int t0     = tq * (S_DIM / TSPLIT);   // 256 * tq

  // ---- q fragments -> registers (64 VGPRs total, held for block) ----
  f32x4 qf[RS][8];
  {
    const float* qb = q + (size_t)b * S_DIM * (H_DIM * D_DIM);
#pragma unroll
    for (int i = 0; i < RS; ++i) {
      const float* qr = qb + (size_t)(s_base + i) * (H_DIM * D_DIM) + h * D_DIM;
#pragma unroll
      for (int dv = 0; dv < 8; ++dv)
        qf[i][dv] = *(const f32x4*)(qr + dv * 4);
    }
  }

  const float* kb = k + (size_t)b * S_DIM * (H_DIM * D_DIM);

  // Staging: thread handles global f32x4 indices g4 = tid + 256*j, j=0..3
  // (coalesced, 16 KB chunk). Swizzled LDS dest for g4=tid is f4a; for
  // g4=tid+256*j it is f4a + 256*j (row increment of 32 leaves the
  // rotation ((dv+row)&7) unchanged mod 8).
  const int f4a = ((tid >> 3) << 3) | (((tid & 7) + (tid >> 3)) & 7);

  // Compute-side read addresses: (row=lane, dv) -> loop-invariant.
  // Second t (row = lane+64) is the same address + 512.
  int raddr[8];
#pragma unroll
  for (int dv = 0; dv < 8; ++dv)
    raddr[dv] = (lane << 3) | ((dv + lane) & 7);

  // ---- prologue: chunk 0 -> LDS buf 0; chunk 1 -> prefetch regs ----
  f32x4 st[4];
  {
    const f32x4* kc0 = (const f32x4*)(kb + (size_t)t0 * (H_DIM * D_DIM));
#pragma unroll
    for (int j = 0; j < 4; ++j) st[j] = kc0[tid + 256 * j];
    f32x4* b0 = (f32x4*)ldsk[0];
#pragma unroll
    for (int j = 0; j < 4; ++j) b0[f4a + 256 * j] = st[j];
    const f32x4* kc1 = (const f32x4*)(kb +
        (size_t)(t0 + TCHUNK) * (H_DIM * D_DIM));
#pragma unroll
    for (int j = 0; j < 4; ++j) st[j] = kc1[tid + 256 * j];
  }

  const float nscale = -0.17677669529663687f;  // -1/sqrt(32)
  float* optr = out +
      ((size_t)(b * S_DIM + s_base) * S_DIM + (size_t)(t0 + t_sub)) * H_DIM + h;

  for (int c = 0; c < NCH; ++c) {
    __syncthreads();   // prev readers of buf^1 done; buf[c&1] fully written

    if (c + 1 < NCH) {           // stage chunk c+1 from regs into buf^1
      f32x4* nb = (f32x4*)ldsk[(c + 1) & 1];
#pragma unroll
      for (int j = 0; j < 4; ++j) nb[f4a + 256 * j] = st[j];
      if (c + 2 < NCH) {         // register-prefetch chunk c+2
        const f32x4* kn = (const f32x4*)(kb +
            (size_t)(t0 + (c + 2) * TCHUNK) * (H_DIM * D_DIM));
#pragma unroll
        for (int j = 0; j < 4; ++j) st[j] = kn[tid + 256 * j];
      }
    }

    const f32x4* kp = (const f32x4*)ldsk[c & 1];
    float a00 = 0.f, a01 = 0.f, a10 = 0.f, a11 = 0.f;  // a[s][t]
#pragma unroll
    for (int dv = 0; dv < 8; ++dv) {
      const f32x4 k0 = kp[raddr[dv]];        // t = t_sub      (rows 0..63)
      const f32x4 k1 = kp[raddr[dv] + 512];  // t = t_sub + 8  (rows 64..127)
      a00 += __builtin_fabsf(qf[0][dv].x - k0.x) + __builtin_fabsf(qf[0][dv].y - k0.y)
           + __builtin_fabsf(qf[0][dv].z - k0.z) + __builtin_fabsf(qf[0][dv].w - k0.w);
      a10 += __builtin_fabsf(qf[1][dv].x - k0.x) + __builtin_fabsf(qf[1][dv].y - k0.y)
           + __builtin_fabsf(qf[1][dv].z - k0.z) + __builtin_fabsf(qf[1][dv].w - k0.w);
      a01 += __builtin_fabsf(qf[0][dv].x - k1.x) + __builtin_fabsf(qf[0][dv].y - k1.y)
           + __builtin_fabsf(qf[0][dv].z - k1.z) + __builtin_fabsf(qf[0][dv].w - k1.w);
      a11 += __builtin_fabsf(qf[1][dv].x - k1.x) + __builtin_fabsf(qf[1][dv].y - k1.y)
           + __builtin_fabsf(qf[1][dv].z - k1.z) + __builtin_fabsf(qf[1][dv].w - k1.w);
    }

    // coalesced dword stores: consecutive lanes -> consecutive (t,h) addrs
    float* o = optr + (size_t)c * (TCHUNK * H_DIM);
    o[0]                              = a00 * nscale;  // (s0, t_sub)
    o[8 * H_DIM]                      = a01 * nscale;  // (s0, t_sub+8)
    o[(size_t)S_DIM * H_DIM]          = a10 * nscale;  // (s1, t_sub)
    o[(size_t)S_DIM * H_DIM + 8 * H_DIM] = a11 * nscale;  // (s1, t_sub+8)
  }
}

extern "C" void kernel_launch(void* const* d_in, const int* in_sizes, int n_in,
                              void* d_out, int out_size, void* d_ws, size_t ws_size,
                              hipStream_t stream) {
  const float* q = (const float*)d_in[0];
  const float* k = (const float*)d_in[1];
  float* out = (float*)d_out;
  const int B = 2;
  dim3 grid(B * (S_DIM / SB) * TSPLIT);   // 4096 blocks
  dim3 block(NTHREADS);
  l1attn_kernel<<<grid, block, 0, stream>>>(q, k, out);
}